// Round 4
// baseline (29710.281 us; speedup 1.0000x reference)
//
#include <hip/hip_runtime.h>
#include <stdint.h>

#define FD 128
#define NNODES 50000
#define NEDGES 800000
#define EB 64  // edges per block

typedef __attribute__((ext_vector_type(8))) short v8s;
typedef __attribute__((ext_vector_type(4))) float v4f;

__device__ __forceinline__ unsigned short f2bf(float f) {
  union { float f; unsigned int u; } v; v.f = f;
  unsigned int r = v.u + 0x7fffu + ((v.u >> 16) & 1u);
  return (unsigned short)(r >> 16);
}
__device__ __forceinline__ float bf2f(unsigned short b) {
  union { unsigned int u; float f; } v; v.u = ((unsigned int)b) << 16;
  return v.f;
}
__device__ __forceinline__ float sspf(float x) {
  float e = __expf(-fabsf(x));
  return fmaxf(x, 0.0f) + __logf(1.0f + e) - 0.6931471805599453f;
}
__device__ __forceinline__ uint2 pack4(float a, float b, float c, float d) {
  uint2 r;
  r.x = (unsigned)f2bf(a) | ((unsigned)f2bf(b) << 16);
  r.y = (unsigned)f2bf(c) | ((unsigned)f2bf(d) << 16);
  return r;
}

// Load this wave's W-fragments (8 x 16B, coalesced) from fragment-packed weights.
__device__ __forceinline__ void load_bfrag(const unsigned short* __restrict__ wfrag,
                                           int l, v8s (&Wf)[2][4]) {
#pragma unroll
  for (int ni = 0; ni < 2; ni++)
#pragma unroll
    for (int kk = 0; kk < 4; kk++)
      Wf[ni][kk] = *(const v8s*)(wfrag + (((ni << 2) + kk) << 9) + (l << 3));
}

// ---------- edge sort by dst (counting sort, once per call) ----------

__global__ void hist_kernel(const int* __restrict__ ed, int* __restrict__ hist) {
  int e = blockIdx.x * 256 + threadIdx.x;
  if (e < NEDGES) atomicAdd(&hist[ed[e]], 1);
}

// exclusive prefix sum over hist[NNODES] -> cursor (single workgroup)
__global__ void scan_kernel(const int* __restrict__ hist, int* __restrict__ cursor) {
  __shared__ int buf[1024];
  __shared__ int carry_s;
  int tid = threadIdx.x;
  if (tid == 0) carry_s = 0;
  __syncthreads();
  for (int base = 0; base < NNODES; base += 1024) {
    int i = base + tid;
    int v = (i < NNODES) ? hist[i] : 0;
    buf[tid] = v;
    __syncthreads();
    for (int off = 1; off < 1024; off <<= 1) {
      int t = (tid >= off) ? buf[tid - off] : 0;
      __syncthreads();
      buf[tid] += t;
      __syncthreads();
    }
    int incl = buf[tid];
    int c = carry_s;
    if (i < NNODES) cursor[i] = c + incl - v;
    __syncthreads();
    if (tid == 1023) carry_s = c + incl;
    __syncthreads();
  }
}

__global__ void scatter_kernel(const int* __restrict__ es, const int* __restrict__ ed,
                               int* __restrict__ cursor, int* __restrict__ es_s,
                               int* __restrict__ ed_s) {
  int e = blockIdx.x * 256 + threadIdx.x;
  if (e >= NEDGES) return;
  int d = ed[e];
  int p = atomicAdd(&cursor[d], 1);
  es_s[p] = es[e];
  ed_s[p] = d;
}

// ---------- prep kernels ----------

__global__ void rbf_kernel(const int* __restrict__ es, const int* __restrict__ ed,
                           const float* __restrict__ pos, float* __restrict__ rbf) {
  int e = blockIdx.x * 256 + threadIdx.x;
  if (e >= NEDGES) return;
  int s = es[e], d = ed[e];
  float dx = pos[s * 3 + 0] - pos[d * 3 + 0];
  float dy = pos[s * 3 + 1] - pos[d * 3 + 1];
  float dz = pos[s * 3 + 2] - pos[d * 3 + 2];
  float D = sqrtf(dx * dx + dy * dy + dz * dz);
  float x = D * 0.1f;
  float cut = 0.0f;
  if (x < 1.0f) {
    float x3 = x * x * x, x4 = x3 * x, x5 = x4 * x;
    cut = 1.0f - 6.0f * x5 + 15.0f * x4 - 10.0f * x3;
  }
  float eD = __expf(-D);
  float em10 = __expf(-10.0f);
  float wdt = 2.5f / (1.0f - em10);
  wdt = wdt * wdt;
#pragma unroll
  for (int k = 0; k < 5; k++) {
    float ck = 1.0f + (float)k * 0.25f * (em10 - 1.0f);
    float t = eD - ck;
    rbf[e * 5 + k] = cut * __expf(-wdt * t * t);
  }
}

// Weights bf16 in MFMA fragment order:
// off = nt*2048 + kk*512 + l*8 + j  holds  W[nt*16+(l&15)][kk*32+(l>>4)*8+j]
// Per block b, 7 matrices: 0:wi 1:wj 2:wd 3:w1_0 4:w2_0 5:w1_1 6:w2_1
__global__ void wconv_kernel(const float* __restrict__ wi, const float* __restrict__ wj,
                             const float* __restrict__ wd, const float* __restrict__ w1,
                             const float* __restrict__ w2, unsigned short* __restrict__ wimg2) {
  int i = blockIdx.x * 256 + threadIdx.x;
  if (i >= 5 * 7 * 16384) return;
  int b = i / (7 * 16384);
  int r = i - b * 7 * 16384;
  int mtx = r >> 14;
  int off = r & 16383;
  int j = off & 7;
  int l = (off >> 3) & 63;
  int kk = (off >> 9) & 3;
  int nt = off >> 11;
  int row = nt * 16 + (l & 15);
  int col = kk * 32 + (l >> 4) * 8 + j;
  const float* src;
  switch (mtx) {
    case 0: src = wi + (size_t)b * 16384; break;
    case 1: src = wj + (size_t)b * 16384; break;
    case 2: src = wd + (size_t)b * 16384; break;
    case 3: src = w1 + (size_t)(b * 2 + 0) * 16384; break;
    case 4: src = w2 + (size_t)(b * 2 + 0) * 16384; break;
    case 5: src = w1 + (size_t)(b * 2 + 1) * 16384; break;
    default: src = w2 + (size_t)(b * 2 + 1) * 16384; break;
  }
  wimg2[(size_t)(b * 7 + mtx) * 16384 + off] = f2bf(src[row * 128 + col]);
}

__global__ void h0_kernel(const int* __restrict__ at, const float* __restrict__ emb,
                          float* __restrict__ h) {
  int i = blockIdx.x * 256 + threadIdx.x;
  int n = i >> 7, c = i & 127;
  h[i] = emb[at[n] * FD + c];
}

// ---------- per-block node kernel: x=ssp(h); hi=x@wi^T+bi (fp32); hj=x@wj^T+bj (bf16) ----------

__global__ __launch_bounds__(256, 4) void node_kernel(
    const float* __restrict__ h, const unsigned short* __restrict__ wblk,
    const float* __restrict__ bi, const float* __restrict__ bj,
    float* __restrict__ hi_f, unsigned short* __restrict__ hj_bf)
{
  __shared__ __align__(16) unsigned short ACT[FD * FD];
  const int tid = threadIdx.x;
  const int wv = tid >> 6;
  const int l = tid & 63;
  const int lc = l & 15;
  const int lg = l >> 4;
  const int cq = wv * 32 + lg * 4;
  const int n0 = blockIdx.x * 128;

  {
    int row = tid >> 1;
    int ch = (tid & 1) * 64;
    int n = n0 + row;
    int x8 = (row & 7) << 3;
#pragma unroll
    for (int q = 0; q < 16; q++) {
      int ce = ch + q * 4;
      v4f hv = (v4f){0.f, 0.f, 0.f, 0.f};
      if (n < NNODES) hv = *(const v4f*)&h[(size_t)n * FD + ce];
      uint2 p = pack4(sspf(hv[0]), sspf(hv[1]), sspf(hv[2]), sspf(hv[3]));
      *(uint2*)&ACT[row * FD + (ce ^ x8)] = p;
    }
  }

  v8s Wfi[2][4], Wfj[2][4];
  load_bfrag(wblk + 0 * 16384 + wv * 4096, l, Wfi);
  load_bfrag(wblk + 1 * 16384 + wv * 4096, l, Wfj);
  v4f biq[2], bjq[2];
#pragma unroll
  for (int ni = 0; ni < 2; ni++) {
    biq[ni] = *(const v4f*)&bi[cq + ni * 16];
    bjq[ni] = *(const v4f*)&bj[cq + ni * 16];
  }
  __syncthreads();

  const int x8 = (lc & 7) << 3;
#pragma unroll 1
  for (int ti = 0; ti < 8; ti++) {
    int node = ti * 16 + lc;
    v8s Af[4];
#pragma unroll
    for (int kk = 0; kk < 4; kk++)
      Af[kk] = *(const v8s*)&ACT[node * FD + ((kk * 32 + lg * 8) ^ x8)];
    v4f ai[2], aj[2];
#pragma unroll
    for (int ni = 0; ni < 2; ni++) { ai[ni] = biq[ni]; aj[ni] = bjq[ni]; }
#pragma unroll
    for (int ni = 0; ni < 2; ni++)
#pragma unroll
      for (int kk = 0; kk < 4; kk++) {
        ai[ni] = __builtin_amdgcn_mfma_f32_16x16x32_bf16(Wfi[ni][kk], Af[kk], ai[ni], 0, 0, 0);
        aj[ni] = __builtin_amdgcn_mfma_f32_16x16x32_bf16(Wfj[ni][kk], Af[kk], aj[ni], 0, 0, 0);
      }
    int n = n0 + node;
    if (n < NNODES) {
#pragma unroll
      for (int ni = 0; ni < 2; ni++) {
        *(v4f*)&hi_f[(size_t)n * FD + cq + ni * 16] = ai[ni];
        *(uint2*)&hj_bf[(size_t)n * FD + cq + ni * 16] =
            pack4(aj[ni][0], aj[ni][1], aj[ni][2], aj[ni][3]);
      }
    }
  }
}

// ---------- per-block fused edge kernel (edges pre-sorted by dst) ----------
// Layers: 0:w1_0 1:w2_0 2:w1_1 3:w2_1 4:wd 5:w1_0 6:w2_0 7:w1_1 8:w2_1
// BIAS LDS rows: 0:rb1_0 1:rb2_0 2:rb1_1 3:rb2_1 4:bd 5:u

__global__ __launch_bounds__(256, 4) void edge_kernel(
    const float* __restrict__ hi_f, const unsigned short* __restrict__ hj_bf,
    const float* __restrict__ rbf, const int* __restrict__ esrc,
    const int* __restrict__ edst, const unsigned short* __restrict__ wblk,
    const float* __restrict__ rb1, const float* __restrict__ rb2,
    const float* __restrict__ bd, const float* __restrict__ uvec,
    const float* __restrict__ k2f, float* __restrict__ outp)
{
  __shared__ __align__(16) unsigned short ACTb[2][EB * FD];  // 32KB double buffer
  __shared__ float BIAS[6 * FD];
  __shared__ float RBF5[EB * 5];
  __shared__ int EDG[2 * EB];

  const int tid = threadIdx.x;
  const int wv = tid >> 6;
  const int l = tid & 63;
  const int lc = l & 15;
  const int lg = l >> 4;
  const int cq = wv * 32 + lg * 4;
  const int x8 = (lc & 7) << 3;
  const int e0 = blockIdx.x * EB;

  for (int i = tid; i < 2 * EB; i += 256)
    EDG[i] = (i < EB) ? esrc[e0 + i] : edst[e0 + i - EB];
  for (int i = tid; i < EB * 5; i += 256) RBF5[i] = rbf[e0 * 5 + i];
  for (int i = tid; i < 6 * FD; i += 256) {
    int which = i >> 7, c = i & 127;
    float v;
    switch (which) {
      case 0: v = rb1[c]; break;
      case 1: v = rb2[c]; break;
      case 2: v = rb1[FD + c]; break;
      case 3: v = rb2[FD + c]; break;
      case 4: v = bd[c]; break;
      default: v = uvec[c]; break;
    }
    BIAS[i] = v;
  }

  v4f kcq[2][5];
#pragma unroll
  for (int ni = 0; ni < 2; ni++)
#pragma unroll
    for (int w = 0; w < 5; w++)
      kcq[ni][w] = *(const v4f*)&k2f[(cq + ni * 16) * 5 + w * 4];

  __syncthreads();

  // init: m = ai + g*hj[src]; ACT[0] = bf16(ssp(m)); skip path m stays fp32
  int dN[4];
  v4f m[2][4];
#pragma unroll
  for (int ei = 0; ei < 4; ei++) {
    int row = ei * 16 + lc;
    int s = EDG[row];
    int d = EDG[EB + row];
    dN[ei] = d;
    float r5[5];
#pragma unroll
    for (int k = 0; k < 5; k++) r5[k] = RBF5[row * 5 + k];
#pragma unroll
    for (int ni = 0; ni < 2; ni++) {
      int c = cq + ni * 16;
      v4f ai = *(const v4f*)&hi_f[(size_t)d * FD + c];
      uint2 hp = *(const uint2*)&hj_bf[(size_t)s * FD + c];
      float hjf[4] = {bf2f((unsigned short)(hp.x & 0xffff)), bf2f((unsigned short)(hp.x >> 16)),
                      bf2f((unsigned short)(hp.y & 0xffff)), bf2f((unsigned short)(hp.y >> 16))};
#pragma unroll
      for (int r = 0; r < 4; r++) {
        float g = 0.f;
#pragma unroll
        for (int k = 0; k < 5; k++) {
          int fi = r * 5 + k;
          g += r5[k] * kcq[ni][fi >> 2][fi & 3];
        }
        m[ni][ei][r] = ai[r] + g * hjf[r];
      }
      *(uint2*)&ACTb[0][row * FD + (c ^ x8)] =
          pack4(sspf(m[ni][ei][0]), sspf(m[ni][ei][1]), sspf(m[ni][ei][2]), sspf(m[ni][ei][3]));
    }
  }

  int buf = 0;
#pragma unroll 1
  for (int L = 0; L < 9; L++) {
    int mat = (L == 4) ? 2 : ((L < 4) ? 3 + L : L - 2);
    v8s Wf[2][4];
    load_bfrag(wblk + mat * 16384 + wv * 4096, l, Wf);

    v4f acc[2][4];
    if (L == 4) {
      v4f uq[2], bq[2];
#pragma unroll
      for (int ni = 0; ni < 2; ni++) {
        uq[ni] = *(const v4f*)&BIAS[5 * FD + cq + ni * 16];
        bq[ni] = *(const v4f*)&BIAS[4 * FD + cq + ni * 16];
      }
#pragma unroll
      for (int ei = 0; ei < 4; ei++) {
        int d = dN[ei];
#pragma unroll
        for (int ni = 0; ni < 2; ni++) {
          v4f ai = *(const v4f*)&hi_f[(size_t)d * FD + cq + ni * 16];
#pragma unroll
          for (int r = 0; r < 4; r++) acc[ni][ei][r] = uq[ni][r] * ai[r] + bq[ni][r];
        }
      }
    } else {
      int bidx = (L < 4) ? L : L - 5;
      v4f bq[2];
#pragma unroll
      for (int ni = 0; ni < 2; ni++) bq[ni] = *(const v4f*)&BIAS[bidx * FD + cq + ni * 16];
#pragma unroll
      for (int ei = 0; ei < 4; ei++)
#pragma unroll
        for (int ni = 0; ni < 2; ni++) acc[ni][ei] = bq[ni];
    }

    __syncthreads();  // ACT[buf] writes done (and prior reads of ACT[buf^1])

    const unsigned short* A = &ACTb[buf][0];
#pragma unroll
    for (int ei = 0; ei < 4; ei++) {
      int rb = (ei * 16 + lc) * FD;
      v8s Af[4];
#pragma unroll
      for (int kk = 0; kk < 4; kk++)
        Af[kk] = *(const v8s*)&A[rb + ((kk * 32 + lg * 8) ^ x8)];
#pragma unroll
      for (int ni = 0; ni < 2; ni++)
#pragma unroll
        for (int kk = 0; kk < 4; kk++)
          acc[ni][ei] = __builtin_amdgcn_mfma_f32_16x16x32_bf16(Wf[ni][kk], Af[kk],
                                                               acc[ni][ei], 0, 0, 0);
    }

    const bool isAcc = (L == 1) || (L == 3) || (L == 6) || (L == 8);
    if (L == 4) {
#pragma unroll
      for (int ei = 0; ei < 4; ei++)
#pragma unroll
        for (int ni = 0; ni < 2; ni++) m[ni][ei] = acc[ni][ei];
    } else if (isAcc) {
#pragma unroll
      for (int ei = 0; ei < 4; ei++)
#pragma unroll
        for (int ni = 0; ni < 2; ni++) m[ni][ei] += acc[ni][ei];
    }

    if (L < 8) {
      const bool wssp = isAcc || (L == 4);
      unsigned short* An = &ACTb[buf ^ 1][0];
#pragma unroll
      for (int ei = 0; ei < 4; ei++) {
        int rb = (ei * 16 + lc) * FD;
#pragma unroll
        for (int ni = 0; ni < 2; ni++) {
          uint2 p;
          if (wssp)
            p = pack4(sspf(m[ni][ei][0]), sspf(m[ni][ei][1]),
                      sspf(m[ni][ei][2]), sspf(m[ni][ei][3]));
          else
            p = pack4(acc[ni][ei][0], acc[ni][ei][1], acc[ni][ei][2], acc[ni][ei][3]);
          *(uint2*)&An[rb + ((cq + ni * 16) ^ x8)] = p;
        }
      }
    }
    buf ^= 1;
  }

  // segment-sum scatter; sorted dst -> atomics stay L2/L1-hot
#pragma unroll
  for (int ei = 0; ei < 4; ei++) {
    int d = dN[ei];
#pragma unroll
    for (int ni = 0; ni < 2; ni++)
#pragma unroll
      for (int r = 0; r < 4; r++)
        atomicAdd(&outp[(size_t)d * FD + cq + ni * 16 + r], m[ni][ei][r]);
  }
}

extern "C" void kernel_launch(void* const* d_in, const int* in_sizes, int n_in,
                              void* d_out, int out_size, void* d_ws, size_t ws_size,
                              hipStream_t stream) {
  (void)in_sizes; (void)n_in; (void)out_size; (void)ws_size;
  const int* at = (const int*)d_in[0];
  const int* es = (const int*)d_in[1];
  const int* ed = (const int*)d_in[2];
  const float* pos = (const float*)d_in[3];
  const float* emb = (const float*)d_in[4];
  const float* k2f = (const float*)d_in[5];
  const float* wi = (const float*)d_in[6];
  const float* bi = (const float*)d_in[7];
  const float* wj = (const float*)d_in[8];
  const float* bj = (const float*)d_in[9];
  const float* wd = (const float*)d_in[10];
  const float* bd = (const float*)d_in[11];
  const float* u = (const float*)d_in[12];
  const float* rw1 = (const float*)d_in[13];
  const float* rb1 = (const float*)d_in[14];
  const float* rw2 = (const float*)d_in[15];
  const float* rb2 = (const float*)d_in[16];

  char* w = (char*)d_ws;
  float* rbf = (float*)w;                     w += (size_t)NEDGES * 5 * 4;
  float* hi_f = (float*)w;                    w += (size_t)NNODES * FD * 4;
  unsigned short* hj_bf = (unsigned short*)w; w += (size_t)NNODES * FD * 2;
  float* hA = (float*)w;                      w += (size_t)NNODES * FD * 4;
  unsigned short* wimg2 = (unsigned short*)w; w += (size_t)5 * 7 * 16384 * 2;
  int* hist = (int*)w;                        w += (size_t)NNODES * 4;
  int* cursor = (int*)w;                      w += (size_t)NNODES * 4;
  int* es_s = (int*)w;                        w += (size_t)NEDGES * 4;
  int* ed_s = (int*)w;                        w += (size_t)NEDGES * 4;

  // --- edge counting-sort by dst (once; reused by all 5 blocks) ---
  hipMemsetAsync(hist, 0, (size_t)NNODES * 4, stream);
  hist_kernel<<<(NEDGES + 255) / 256, 256, 0, stream>>>(ed, hist);
  scan_kernel<<<1, 1024, 0, stream>>>(hist, cursor);
  scatter_kernel<<<(NEDGES + 255) / 256, 256, 0, stream>>>(es, ed, cursor, es_s, ed_s);

  rbf_kernel<<<(NEDGES + 255) / 256, 256, 0, stream>>>(es_s, ed_s, pos, rbf);
  wconv_kernel<<<(5 * 7 * 16384 + 255) / 256, 256, 0, stream>>>(wi, wj, wd, rw1, rw2, wimg2);
  h0_kernel<<<(NNODES * FD) / 256, 256, 0, stream>>>(at, emb, hA);

  // h ping-pongs between hA and d_out; final block lands in d_out.
  float* hcur = hA;
  for (int b = 0; b < 5; b++) {
    node_kernel<<<(NNODES + 127) / 128, 256, 0, stream>>>(
        hcur, wimg2 + (size_t)b * 7 * 16384, bi + b * FD, bj + b * FD, hi_f, hj_bf);
    float* tgt = (b & 1) ? hA : (float*)d_out;
    hipMemsetAsync(tgt, 0, (size_t)NNODES * FD * 4, stream);
    edge_kernel<<<NEDGES / EB, 256, 0, stream>>>(
        hi_f, hj_bf, rbf, es_s, ed_s, wimg2 + (size_t)b * 7 * 16384,
        rb1 + (size_t)b * 2 * FD, rb2 + (size_t)b * 2 * FD, bd + b * FD,
        u + b * FD, k2f + (size_t)b * FD * 5, tgt);
    hcur = tgt;
  }
}

// Round 5
// 6034.814 us; speedup vs baseline: 4.9231x; 4.9231x over previous
//
#include <hip/hip_runtime.h>
#include <stdint.h>

#define FD 128
#define NNODES 50000
#define NEDGES 800000
#define EB 64  // edges per block
#define NWG (NEDGES / EB)

typedef __attribute__((ext_vector_type(8))) short v8s;
typedef __attribute__((ext_vector_type(4))) float v4f;

__device__ __forceinline__ unsigned short f2bf(float f) {
  union { float f; unsigned int u; } v; v.f = f;
  unsigned int r = v.u + 0x7fffu + ((v.u >> 16) & 1u);
  return (unsigned short)(r >> 16);
}
__device__ __forceinline__ float bf2f(unsigned short b) {
  union { unsigned int u; float f; } v; v.u = ((unsigned int)b) << 16;
  return v.f;
}
__device__ __forceinline__ float sspf(float x) {
  float e = __expf(-fabsf(x));
  return fmaxf(x, 0.0f) + __logf(1.0f + e) - 0.6931471805599453f;
}
__device__ __forceinline__ uint2 pack4(float a, float b, float c, float d) {
  uint2 r;
  r.x = (unsigned)f2bf(a) | ((unsigned)f2bf(b) << 16);
  r.y = (unsigned)f2bf(c) | ((unsigned)f2bf(d) << 16);
  return r;
}

// Load this wave's W-fragments (8 x 16B, coalesced) from fragment-packed weights.
__device__ __forceinline__ void load_bfrag(const unsigned short* __restrict__ wfrag,
                                           int l, v8s (&Wf)[2][4]) {
#pragma unroll
  for (int ni = 0; ni < 2; ni++)
#pragma unroll
    for (int kk = 0; kk < 4; kk++)
      Wf[ni][kk] = *(const v8s*)(wfrag + (((ni << 2) + kk) << 9) + (l << 3));
}

// ---------- edge sort by dst (counting sort, once per call) ----------

__global__ void hist_kernel(const int* __restrict__ ed, int* __restrict__ hist) {
  int e = blockIdx.x * 256 + threadIdx.x;
  if (e < NEDGES) atomicAdd(&hist[ed[e]], 1);
}

// exclusive prefix sum over hist[NNODES] -> cursor (single workgroup)
__global__ void scan_kernel(const int* __restrict__ hist, int* __restrict__ cursor) {
  __shared__ int buf[1024];
  __shared__ int carry_s;
  int tid = threadIdx.x;
  if (tid == 0) carry_s = 0;
  __syncthreads();
  for (int base = 0; base < NNODES; base += 1024) {
    int i = base + tid;
    int v = (i < NNODES) ? hist[i] : 0;
    buf[tid] = v;
    __syncthreads();
    for (int off = 1; off < 1024; off <<= 1) {
      int t = (tid >= off) ? buf[tid - off] : 0;
      __syncthreads();
      buf[tid] += t;
      __syncthreads();
    }
    int incl = buf[tid];
    int c = carry_s;
    if (i < NNODES) cursor[i] = c + incl - v;
    __syncthreads();
    if (tid == 1023) carry_s = c + incl;
    __syncthreads();
  }
}

__global__ void scatter_kernel(const int* __restrict__ es, const int* __restrict__ ed,
                               int* __restrict__ cursor, int* __restrict__ es_s,
                               int* __restrict__ ed_s) {
  int e = blockIdx.x * 256 + threadIdx.x;
  if (e >= NEDGES) return;
  int d = ed[e];
  int p = atomicAdd(&cursor[d], 1);
  es_s[p] = es[e];
  ed_s[p] = d;
}

// ---------- prep kernels ----------

__global__ void rbf_kernel(const int* __restrict__ es, const int* __restrict__ ed,
                           const float* __restrict__ pos, float* __restrict__ rbf) {
  int e = blockIdx.x * 256 + threadIdx.x;
  if (e >= NEDGES) return;
  int s = es[e], d = ed[e];
  float dx = pos[s * 3 + 0] - pos[d * 3 + 0];
  float dy = pos[s * 3 + 1] - pos[d * 3 + 1];
  float dz = pos[s * 3 + 2] - pos[d * 3 + 2];
  float D = sqrtf(dx * dx + dy * dy + dz * dz);
  float x = D * 0.1f;
  float cut = 0.0f;
  if (x < 1.0f) {
    float x3 = x * x * x, x4 = x3 * x, x5 = x4 * x;
    cut = 1.0f - 6.0f * x5 + 15.0f * x4 - 10.0f * x3;
  }
  float eD = __expf(-D);
  float em10 = __expf(-10.0f);
  float wdt = 2.5f / (1.0f - em10);
  wdt = wdt * wdt;
#pragma unroll
  for (int k = 0; k < 5; k++) {
    float ck = 1.0f + (float)k * 0.25f * (em10 - 1.0f);
    float t = eD - ck;
    rbf[e * 5 + k] = cut * __expf(-wdt * t * t);
  }
}

// Weights bf16 in MFMA fragment order:
// off = nt*2048 + kk*512 + l*8 + j  holds  W[nt*16+(l&15)][kk*32+(l>>4)*8+j]
// Per block b, 7 matrices: 0:wi 1:wj 2:wd 3:w1_0 4:w2_0 5:w1_1 6:w2_1
__global__ void wconv_kernel(const float* __restrict__ wi, const float* __restrict__ wj,
                             const float* __restrict__ wd, const float* __restrict__ w1,
                             const float* __restrict__ w2, unsigned short* __restrict__ wimg2) {
  int i = blockIdx.x * 256 + threadIdx.x;
  if (i >= 5 * 7 * 16384) return;
  int b = i / (7 * 16384);
  int r = i - b * 7 * 16384;
  int mtx = r >> 14;
  int off = r & 16383;
  int j = off & 7;
  int l = (off >> 3) & 63;
  int kk = (off >> 9) & 3;
  int nt = off >> 11;
  int row = nt * 16 + (l & 15);
  int col = kk * 32 + (l >> 4) * 8 + j;
  const float* src;
  switch (mtx) {
    case 0: src = wi + (size_t)b * 16384; break;
    case 1: src = wj + (size_t)b * 16384; break;
    case 2: src = wd + (size_t)b * 16384; break;
    case 3: src = w1 + (size_t)(b * 2 + 0) * 16384; break;
    case 4: src = w2 + (size_t)(b * 2 + 0) * 16384; break;
    case 5: src = w1 + (size_t)(b * 2 + 1) * 16384; break;
    default: src = w2 + (size_t)(b * 2 + 1) * 16384; break;
  }
  wimg2[(size_t)(b * 7 + mtx) * 16384 + off] = f2bf(src[row * 128 + col]);
}

__global__ void h0_kernel(const int* __restrict__ at, const float* __restrict__ emb,
                          float* __restrict__ h) {
  int i = blockIdx.x * 256 + threadIdx.x;
  int n = i >> 7, c = i & 127;
  h[i] = emb[at[n] * FD + c];
}

// ---------- per-block node kernel: x=ssp(h); hi=x@wi^T+bi (fp32); hj=x@wj^T+bj (bf16) ----------

__global__ __launch_bounds__(256, 4) void node_kernel(
    const float* __restrict__ h, const unsigned short* __restrict__ wblk,
    const float* __restrict__ bi, const float* __restrict__ bj,
    float* __restrict__ hi_f, unsigned short* __restrict__ hj_bf)
{
  __shared__ __align__(16) unsigned short ACT[FD * FD];
  const int tid = threadIdx.x;
  const int wv = tid >> 6;
  const int l = tid & 63;
  const int lc = l & 15;
  const int lg = l >> 4;
  const int cq = wv * 32 + lg * 4;
  const int n0 = blockIdx.x * 128;

  {
    int row = tid >> 1;
    int ch = (tid & 1) * 64;
    int n = n0 + row;
    int x8 = (row & 7) << 3;
#pragma unroll
    for (int q = 0; q < 16; q++) {
      int ce = ch + q * 4;
      v4f hv = (v4f){0.f, 0.f, 0.f, 0.f};
      if (n < NNODES) hv = *(const v4f*)&h[(size_t)n * FD + ce];
      uint2 p = pack4(sspf(hv[0]), sspf(hv[1]), sspf(hv[2]), sspf(hv[3]));
      *(uint2*)&ACT[row * FD + (ce ^ x8)] = p;
    }
  }

  v8s Wfi[2][4], Wfj[2][4];
  load_bfrag(wblk + 0 * 16384 + wv * 4096, l, Wfi);
  load_bfrag(wblk + 1 * 16384 + wv * 4096, l, Wfj);
  v4f biq[2], bjq[2];
#pragma unroll
  for (int ni = 0; ni < 2; ni++) {
    biq[ni] = *(const v4f*)&bi[cq + ni * 16];
    bjq[ni] = *(const v4f*)&bj[cq + ni * 16];
  }
  __syncthreads();

  const int x8 = (lc & 7) << 3;
#pragma unroll 1
  for (int ti = 0; ti < 8; ti++) {
    int node = ti * 16 + lc;
    v8s Af[4];
#pragma unroll
    for (int kk = 0; kk < 4; kk++)
      Af[kk] = *(const v8s*)&ACT[node * FD + ((kk * 32 + lg * 8) ^ x8)];
    v4f ai[2], aj[2];
#pragma unroll
    for (int ni = 0; ni < 2; ni++) { ai[ni] = biq[ni]; aj[ni] = bjq[ni]; }
#pragma unroll
    for (int ni = 0; ni < 2; ni++)
#pragma unroll
      for (int kk = 0; kk < 4; kk++) {
        ai[ni] = __builtin_amdgcn_mfma_f32_16x16x32_bf16(Wfi[ni][kk], Af[kk], ai[ni], 0, 0, 0);
        aj[ni] = __builtin_amdgcn_mfma_f32_16x16x32_bf16(Wfj[ni][kk], Af[kk], aj[ni], 0, 0, 0);
      }
    int n = n0 + node;
    if (n < NNODES) {
#pragma unroll
      for (int ni = 0; ni < 2; ni++) {
        *(v4f*)&hi_f[(size_t)n * FD + cq + ni * 16] = ai[ni];
        *(uint2*)&hj_bf[(size_t)n * FD + cq + ni * 16] =
            pack4(aj[ni][0], aj[ni][1], aj[ni][2], aj[ni][3]);
      }
    }
  }
}

// ---------- per-block fused edge kernel (edges pre-sorted by dst) ----------
// Layers: 0:w1_0 1:w2_0 2:w1_1 3:w2_1 4:wd 5:w1_0 6:w2_0 7:w1_1 8:w2_1
// Epilogue: block-private segmented reduction in LDS, one write per segment.

__global__ __launch_bounds__(256, 4) void edge_kernel(
    const float* __restrict__ hi_f, const unsigned short* __restrict__ hj_bf,
    const float* __restrict__ rbf, const int* __restrict__ esrc,
    const int* __restrict__ edst, const unsigned short* __restrict__ wblk,
    const float* __restrict__ rb1, const float* __restrict__ rb2,
    const float* __restrict__ bd, const float* __restrict__ uvec,
    const float* __restrict__ k2f, float* __restrict__ outp)
{
  __shared__ __align__(16) unsigned short ACTb[2][EB * FD];  // 32KB; reused as SEGF
  __shared__ float BIAS[6 * FD];
  __shared__ float RBF5[EB * 5];
  __shared__ int EDG[2 * EB];
  __shared__ int SEGID[EB];
  __shared__ int SEGD[EB];
  __shared__ int nseg_s, share_lo_s, share_hi_s;

  const int tid = threadIdx.x;
  const int wv = tid >> 6;
  const int l = tid & 63;
  const int lc = l & 15;
  const int lg = l >> 4;
  const int cq = wv * 32 + lg * 4;
  const int x8 = (lc & 7) << 3;

  // bijective XCD-chunked swizzle (m204): consecutive logical blocks -> same XCD
  int wg;
  {
    const int q = NWG >> 3, r = NWG & 7;
    int x = blockIdx.x & 7, idx = blockIdx.x >> 3;
    wg = (x < r ? x * (q + 1) : r * (q + 1) + (x - r) * q) + idx;
  }
  const int e0 = wg * EB;

  for (int i = tid; i < 2 * EB; i += 256)
    EDG[i] = (i < EB) ? esrc[e0 + i] : edst[e0 + i - EB];
  for (int i = tid; i < EB * 5; i += 256) RBF5[i] = rbf[e0 * 5 + i];
  for (int i = tid; i < 6 * FD; i += 256) {
    int which = i >> 7, c = i & 127;
    float v;
    switch (which) {
      case 0: v = rb1[c]; break;
      case 1: v = rb2[c]; break;
      case 2: v = rb1[FD + c]; break;
      case 3: v = rb2[FD + c]; break;
      case 4: v = bd[c]; break;
      default: v = uvec[c]; break;
    }
    BIAS[i] = v;
  }

  v4f kcq[2][5];
#pragma unroll
  for (int ni = 0; ni < 2; ni++)
#pragma unroll
    for (int w = 0; w < 5; w++)
      kcq[ni][w] = *(const v4f*)&k2f[(cq + ni * 16) * 5 + w * 4];

  __syncthreads();

  // segment ids over sorted dst (wave 0 only, ballot over 64 lanes)
  if (tid < 64) {
    int d = EDG[EB + tid];
    int pd = (tid == 0) ? -1 : EDG[EB + tid - 1];
    bool bnd = (tid == 0) || (d != pd);
    unsigned long long msk = __ballot(bnd);
    int sid = (int)__popcll(msk & ((2ull << tid) - 1)) - 1;
    SEGID[tid] = sid;
    if (bnd) SEGD[sid] = d;
    if (tid == 0) {
      nseg_s = (int)__popcll(msk);
      share_lo_s = (e0 > 0) && (d == edst[e0 - 1]);
    }
    if (tid == 63) share_hi_s = (e0 + EB < NEDGES) && (d == edst[e0 + EB]);
  }

  // init: m = ai + g*hj[src]; ACT[0] = bf16(ssp(m)); skip path m stays fp32
  int dN[4];
  v4f m[2][4];
#pragma unroll
  for (int ei = 0; ei < 4; ei++) {
    int row = ei * 16 + lc;
    int s = EDG[row];
    int d = EDG[EB + row];
    dN[ei] = d;
    float r5[5];
#pragma unroll
    for (int k = 0; k < 5; k++) r5[k] = RBF5[row * 5 + k];
#pragma unroll
    for (int ni = 0; ni < 2; ni++) {
      int c = cq + ni * 16;
      v4f ai = *(const v4f*)&hi_f[(size_t)d * FD + c];
      uint2 hp = *(const uint2*)&hj_bf[(size_t)s * FD + c];
      float hjf[4] = {bf2f((unsigned short)(hp.x & 0xffff)), bf2f((unsigned short)(hp.x >> 16)),
                      bf2f((unsigned short)(hp.y & 0xffff)), bf2f((unsigned short)(hp.y >> 16))};
#pragma unroll
      for (int r = 0; r < 4; r++) {
        float g = 0.f;
#pragma unroll
        for (int k = 0; k < 5; k++) {
          int fi = r * 5 + k;
          g += r5[k] * kcq[ni][fi >> 2][fi & 3];
        }
        m[ni][ei][r] = ai[r] + g * hjf[r];
      }
      *(uint2*)&ACTb[0][row * FD + (c ^ x8)] =
          pack4(sspf(m[ni][ei][0]), sspf(m[ni][ei][1]), sspf(m[ni][ei][2]), sspf(m[ni][ei][3]));
    }
  }

  int buf = 0;
#pragma unroll 1
  for (int L = 0; L < 9; L++) {
    int mat = (L == 4) ? 2 : ((L < 4) ? 3 + L : L - 2);
    v8s Wf[2][4];
    load_bfrag(wblk + mat * 16384 + wv * 4096, l, Wf);

    v4f acc[2][4];
    if (L == 4) {
      v4f uq[2], bq[2];
#pragma unroll
      for (int ni = 0; ni < 2; ni++) {
        uq[ni] = *(const v4f*)&BIAS[5 * FD + cq + ni * 16];
        bq[ni] = *(const v4f*)&BIAS[4 * FD + cq + ni * 16];
      }
#pragma unroll
      for (int ei = 0; ei < 4; ei++) {
        int d = dN[ei];
#pragma unroll
        for (int ni = 0; ni < 2; ni++) {
          v4f ai = *(const v4f*)&hi_f[(size_t)d * FD + cq + ni * 16];
#pragma unroll
          for (int r = 0; r < 4; r++) acc[ni][ei][r] = uq[ni][r] * ai[r] + bq[ni][r];
        }
      }
    } else {
      int bidx = (L < 4) ? L : L - 5;
      v4f bq[2];
#pragma unroll
      for (int ni = 0; ni < 2; ni++) bq[ni] = *(const v4f*)&BIAS[bidx * FD + cq + ni * 16];
#pragma unroll
      for (int ei = 0; ei < 4; ei++)
#pragma unroll
        for (int ni = 0; ni < 2; ni++) acc[ni][ei] = bq[ni];
    }

    __syncthreads();  // ACT[buf] writes done (and prior reads of ACT[buf^1])

    const unsigned short* A = &ACTb[buf][0];
#pragma unroll
    for (int ei = 0; ei < 4; ei++) {
      int rb = (ei * 16 + lc) * FD;
      v8s Af[4];
#pragma unroll
      for (int kk = 0; kk < 4; kk++)
        Af[kk] = *(const v8s*)&A[rb + ((kk * 32 + lg * 8) ^ x8)];
#pragma unroll
      for (int ni = 0; ni < 2; ni++)
#pragma unroll
        for (int kk = 0; kk < 4; kk++)
          acc[ni][ei] = __builtin_amdgcn_mfma_f32_16x16x32_bf16(Wf[ni][kk], Af[kk],
                                                               acc[ni][ei], 0, 0, 0);
    }

    const bool isAcc = (L == 1) || (L == 3) || (L == 6) || (L == 8);
    if (L == 4) {
#pragma unroll
      for (int ei = 0; ei < 4; ei++)
#pragma unroll
        for (int ni = 0; ni < 2; ni++) m[ni][ei] = acc[ni][ei];
    } else if (isAcc) {
#pragma unroll
      for (int ei = 0; ei < 4; ei++)
#pragma unroll
        for (int ni = 0; ni < 2; ni++) m[ni][ei] += acc[ni][ei];
    }

    if (L < 8) {
      const bool wssp = isAcc || (L == 4);
      unsigned short* An = &ACTb[buf ^ 1][0];
#pragma unroll
      for (int ei = 0; ei < 4; ei++) {
        int rb = (ei * 16 + lc) * FD;
#pragma unroll
        for (int ni = 0; ni < 2; ni++) {
          uint2 p;
          if (wssp)
            p = pack4(sspf(m[ni][ei][0]), sspf(m[ni][ei][1]),
                      sspf(m[ni][ei][2]), sspf(m[ni][ei][3]));
          else
            p = pack4(acc[ni][ei][0], acc[ni][ei][1], acc[ni][ei][2], acc[ni][ei][3]);
          *(uint2*)&An[rb + ((cq + ni * 16) ^ x8)] = p;
        }
      }
    }
    buf ^= 1;
  }

  // ---- epilogue: block-private segmented reduction ----
  __syncthreads();  // last mfma reads of ACTb done; safe to reuse as SEGF
  float* SEGF = (float*)&ACTb[0][0];  // [nseg][128] fp32, nseg<=64
  const int ns = nseg_s;
  for (int i = tid; i < ns * FD; i += 256) SEGF[i] = 0.f;
  __syncthreads();

  // accumulate with run-length combine over ei (rows ei*16+lc share dst often)
  {
    int sid[4];
#pragma unroll
    for (int ei = 0; ei < 4; ei++) sid[ei] = SEGID[ei * 16 + lc];
#pragma unroll
    for (int ni = 0; ni < 2; ni++) {
      v4f run = m[ni][0];
      int cs = sid[0];
#pragma unroll
      for (int ei = 1; ei < 4; ei++) {
        if (sid[ei] == cs) {
          run += m[ni][ei];
        } else {
#pragma unroll
          for (int r = 0; r < 4; r++)
            atomicAdd(&SEGF[cs * FD + cq + ni * 16 + r], run[r]);
          run = m[ni][ei];
          cs = sid[ei];
        }
      }
#pragma unroll
      for (int r = 0; r < 4; r++)
        atomicAdd(&SEGF[cs * FD + cq + ni * 16 + r], run[r]);
    }
  }
  __syncthreads();

  // flush: one coalesced write per segment row; atomics only for boundary segs
  {
    const int shlo = share_lo_s, shhi = share_hi_s;
    for (int i = tid; i < ns * 32; i += 256) {
      int s = i >> 5;
      int c4 = (i & 31) * 4;
      int d = SEGD[s];
      v4f v = *(v4f*)&SEGF[s * FD + c4];
      bool boundary = (s == 0 && shlo) || (s == ns - 1 && shhi);
      float* dst = &outp[(size_t)d * FD + c4];
      if (boundary) {
#pragma unroll
        for (int r = 0; r < 4; r++) atomicAdd(dst + r, v[r]);
      } else {
        *(v4f*)dst = v;
      }
    }
  }
}

extern "C" void kernel_launch(void* const* d_in, const int* in_sizes, int n_in,
                              void* d_out, int out_size, void* d_ws, size_t ws_size,
                              hipStream_t stream) {
  (void)in_sizes; (void)n_in; (void)out_size; (void)ws_size;
  const int* at = (const int*)d_in[0];
  const int* es = (const int*)d_in[1];
  const int* ed = (const int*)d_in[2];
  const float* pos = (const float*)d_in[3];
  const float* emb = (const float*)d_in[4];
  const float* k2f = (const float*)d_in[5];
  const float* wi = (const float*)d_in[6];
  const float* bi = (const float*)d_in[7];
  const float* wj = (const float*)d_in[8];
  const float* bj = (const float*)d_in[9];
  const float* wd = (const float*)d_in[10];
  const float* bd = (const float*)d_in[11];
  const float* u = (const float*)d_in[12];
  const float* rw1 = (const float*)d_in[13];
  const float* rb1 = (const float*)d_in[14];
  const float* rw2 = (const float*)d_in[15];
  const float* rb2 = (const float*)d_in[16];

  char* w = (char*)d_ws;
  float* rbf = (float*)w;                     w += (size_t)NEDGES * 5 * 4;
  float* hi_f = (float*)w;                    w += (size_t)NNODES * FD * 4;
  unsigned short* hj_bf = (unsigned short*)w; w += (size_t)NNODES * FD * 2;
  float* hA = (float*)w;                      w += (size_t)NNODES * FD * 4;
  unsigned short* wimg2 = (unsigned short*)w; w += (size_t)5 * 7 * 16384 * 2;
  int* hist = (int*)w;                        w += (size_t)NNODES * 4;
  int* cursor = (int*)w;                      w += (size_t)NNODES * 4;
  int* es_s = (int*)w;                        w += (size_t)NEDGES * 4;
  int* ed_s = (int*)w;                        w += (size_t)NEDGES * 4;

  // --- edge counting-sort by dst (once; reused by all 5 blocks) ---
  hipMemsetAsync(hist, 0, (size_t)NNODES * 4, stream);
  hist_kernel<<<(NEDGES + 255) / 256, 256, 0, stream>>>(ed, hist);
  scan_kernel<<<1, 1024, 0, stream>>>(hist, cursor);
  scatter_kernel<<<(NEDGES + 255) / 256, 256, 0, stream>>>(es, ed, cursor, es_s, ed_s);

  rbf_kernel<<<(NEDGES + 255) / 256, 256, 0, stream>>>(es_s, ed_s, pos, rbf);
  wconv_kernel<<<(5 * 7 * 16384 + 255) / 256, 256, 0, stream>>>(wi, wj, wd, rw1, rw2, wimg2);
  h0_kernel<<<(NNODES * FD) / 256, 256, 0, stream>>>(at, emb, hA);

  // h ping-pongs between hA and d_out; final block lands in d_out.
  float* hcur = hA;
  for (int b = 0; b < 5; b++) {
    node_kernel<<<(NNODES + 127) / 128, 256, 0, stream>>>(
        hcur, wimg2 + (size_t)b * 7 * 16384, bi + b * FD, bj + b * FD, hi_f, hj_bf);
    float* tgt = (b & 1) ? hA : (float*)d_out;
    hipMemsetAsync(tgt, 0, (size_t)NNODES * FD * 4, stream);
    edge_kernel<<<NWG, 256, 0, stream>>>(
        hi_f, hj_bf, rbf, es_s, ed_s, wimg2 + (size_t)b * 7 * 16384,
        rb1 + (size_t)b * 2 * FD, rb2 + (size_t)b * 2 * FD, bd + b * FD,
        u + b * FD, k2f + (size_t)b * FD * 5, tgt);
    hcur = tgt;
  }
}